// Round 7
// baseline (40.978 us; speedup 1.0000x reference)
//
#include <hip/hip_runtime.h>
#include <hip/hip_bf16.h>
#include <math.h>

// Problem constants
#define Bn    8
#define Sn    8
#define COUTc 128
#define PWc   73728
#define Pc    73856
#define WOc   30
#define NPIX  900      // 30*30 per (b,s)
#define GPIX  7200     // B*NPIX per s
#define NSTEP 9        // one r=(ky,kx) per K-step, 64 ci each

typedef __bf16 bf16;
typedef bf16  bf16x8 __attribute__((ext_vector_type(8)));
typedef float f32x16 __attribute__((ext_vector_type(16)));

__device__ __forceinline__ float softplus_f(float x) {
    return fmaxf(x, 0.f) + log1pf(expf(-fabsf(x)));
}

__device__ __forceinline__ unsigned int pack2(float a, float b) {
    unsigned short ua = __builtin_bit_cast(unsigned short, (bf16)a);
    unsigned short ub = __builtin_bit_cast(unsigned short, (bf16)b);
    return ((unsigned int)ub << 16) | (unsigned int)ua;
}

// ---------------------------------------------------------------------------
// Kernel 1 (fused):
//  blocks 0..511  : xcast  x fp32 NCHW -> xt bf16 octet-major
//                   xt chunk16[(img*8 + oct)*1024 + yx] = 8 ci of octet `oct`
//  blocks 512..543: W sampling, thread = (co,ci), 9 contiguous taps
//                   wq chunk16[(s*9+r)*1024 + oct*128 + co], oct = ci>>3
//  block  544     : bias sampling
//  Prep blocks write KL partials to slots[33*2] unconditionally.
// ---------------------------------------------------------------------------
__global__ __launch_bounds__(256) void prep_all(
        const float* __restrict__ xg, const float* __restrict__ e,
        const float* __restrict__ mu_w, const float* __restrict__ rho_w,
        const float* __restrict__ mu_b, const float* __restrict__ rho_b,
        bf16* __restrict__ xt, bf16* __restrict__ wq,
        float* __restrict__ bq, float* __restrict__ slots) {
    const int bid = blockIdx.x;
    const int t   = threadIdx.x;

    if (bid < 512) {  // ---- xcast -> octet-major
        const int img  = bid >> 3;
        const int part = bid & 7;
        const int p    = part * 128 + (t & 127);   // yx 0..1023
        const int half = t >> 7;                   // which 32-ci block
        const float* src = xg + ((size_t)img << 16) + (size_t)(half * 32) * 1024 + p;
        #pragma unroll
        for (int o = 0; o < 4; ++o) {
            uint4 pk;
            pk.x = pack2(src[(o * 8 + 0) * 1024], src[(o * 8 + 1) * 1024]);
            pk.y = pack2(src[(o * 8 + 2) * 1024], src[(o * 8 + 3) * 1024]);
            pk.z = pack2(src[(o * 8 + 4) * 1024], src[(o * 8 + 5) * 1024]);
            pk.w = pack2(src[(o * 8 + 6) * 1024], src[(o * 8 + 7) * 1024]);
            size_t idx16 = ((size_t)(img * 8 + half * 4 + o) << 10) + p;
            *reinterpret_cast<uint4*>(xt + (idx16 << 3)) = pk;
        }
        return;
    }

    float ls = 0.f, sq = 0.f;
    if (bid < 544) {  // ---- W prep: thread = one (co,ci) pair, 9 taps
        const int gidx = (bid - 512) * 256 + t;   // 0..8191
        const int co   = gidx >> 6;
        const int ci   = gidx & 63;
        const int p0   = co * 576 + ci * 9;
        float mu[9], sg[9];
        #pragma unroll
        for (int r = 0; r < 9; ++r) {
            mu[r] = mu_w[p0 + r];
            sg[r] = softplus_f(rho_w[p0 + r]);
            ls   += logf(sg[r]);
        }
        // dst bf16 index: ((s*9+r)*1024 + (ci>>3)*128 + co)*8 + (ci&7)
        const int dstp = ((((ci >> 3) << 7) + co) << 3) + (ci & 7);
        #pragma unroll
        for (int s = 0; s < Sn; ++s) {
            const float* es = e + s * Pc + p0;
            #pragma unroll
            for (int r = 0; r < 9; ++r) {
                float wv = fmaf(sg[r], es[r], mu[r]);
                wq[(((s * NSTEP + r) << 10) << 3) + dstp] = (bf16)wv;
                sq += wv * wv;
            }
        }
    } else {          // ---- bias prep (bid == 544)
        if (t < COUTc) {
            float sig = softplus_f(rho_b[t]);
            ls = logf(sig);
            float mu = mu_b[t];
            #pragma unroll
            for (int s = 0; s < Sn; ++s) {
                float bv = fmaf(sig, e[s * Pc + PWc + t], mu);
                bq[s * COUTc + t] = bv;
                sq += bv * bv;
            }
        }
    }

    #pragma unroll
    for (int off = 32; off > 0; off >>= 1) {
        ls += __shfl_down(ls, off);
        sq += __shfl_down(sq, off);
    }
    __shared__ float sls[4], ssq[4];
    const int lane = t & 63, wd = t >> 6;
    if (lane == 0) { sls[wd] = ls; ssq[wd] = sq; }
    __syncthreads();
    if (t == 0) {
        slots[2 * (bid - 512)]     = sls[0] + sls[1] + sls[2] + sls[3];
        slots[2 * (bid - 512) + 1] = ssq[0] + ssq[1] + ssq[2] + ssq[3];
    }
}

// ---------------------------------------------------------------------------
// Kernel 2: barrier-free, LDS-free implicit-GEMM conv.
// One 64-thread block = one wave = one 64co x 64pix x s tile.
// A/B fragments loaded straight from L2 (octet-major layouts -> lanes 0-31
// read 512 B contiguous, lanes 32-63 the next octet). Fully unrolled 9x4
// K-loop (mfma_f32_32x32x16_bf16); no __syncthreads anywhere.
// Grid 1808 = 8 s (bid&7, XCD-affine) x 113 pixtiles x 2 co-halves.
// ---------------------------------------------------------------------------
__global__ __launch_bounds__(64) void conv_mfma(
        const bf16* __restrict__ xt, const bf16* __restrict__ wq,
        const float* __restrict__ bq, const float* __restrict__ slots,
        float* __restrict__ out, float* __restrict__ klout) {
    const int bid  = blockIdx.x;
    const int s    = bid & 7;
    const int idx  = bid >> 3;        // 0..225
    const int coh  = idx & 1;         // co half
    const int pt   = idx >> 1;        // pix tile 0..112
    const int lane = threadIdx.x;
    const int hi   = lane >> 5;       // octet parity within k-chunk
    const int lo   = lane & 31;

    // W frag base: chunk16 = (s*9 + r)*1024 + (kc*2+hi)*128 + coh*64 + i*32 + lo
    const bf16* wp = wq + ((((size_t)(s * NSTEP) << 10) + hi * 128 + coh * 64 + lo) << 3);

    // X frag bases for the two 32-pix columns
    const bf16 *xp0, *xp1;
    int g0, g1;
    {
        int g = pt * 64 + lo;         g0 = g; if (g > GPIX - 1) g = GPIX - 1;
        int b2 = g / NPIX, rr = g - b2 * NPIX, oy = rr / WOc, ox = rr - oy * WOc;
        xp0 = xt + ((((size_t)((b2 * Sn + s) * 8 + hi) << 10) + oy * 32 + ox) << 3);
        g = pt * 64 + 32 + lo;        g1 = g; if (g > GPIX - 1) g = GPIX - 1;
        b2 = g / NPIX; rr = g - b2 * NPIX; oy = rr / WOc; ox = rr - oy * WOc;
        xp1 = xt + ((((size_t)((b2 * Sn + s) * 8 + hi) << 10) + oy * 32 + ox) << 3);
    }

    f32x16 acc00, acc01, acc10, acc11;
    #pragma unroll
    for (int k = 0; k < 16; ++k) { acc00[k] = 0.f; acc01[k] = 0.f; acc10[k] = 0.f; acc11[k] = 0.f; }

    #pragma unroll
    for (int r = 0; r < NSTEP; ++r) {
        const int dyx = (r / 3) * 32 + (r % 3);   // constant after unroll
        #pragma unroll
        for (int kc = 0; kc < 4; ++kc) {
            bf16x8 a0 = *reinterpret_cast<const bf16x8*>(wp + (((r << 10) + kc * 256) << 3));
            bf16x8 a1 = *reinterpret_cast<const bf16x8*>(wp + (((r << 10) + kc * 256 + 32) << 3));
            bf16x8 b0 = *reinterpret_cast<const bf16x8*>(xp0 + ((kc * 2048 + dyx) << 3));
            bf16x8 b1 = *reinterpret_cast<const bf16x8*>(xp1 + ((kc * 2048 + dyx) << 3));
            acc00 = __builtin_amdgcn_mfma_f32_32x32x16_bf16(a0, b0, acc00, 0, 0, 0);
            acc01 = __builtin_amdgcn_mfma_f32_32x32x16_bf16(a0, b1, acc01, 0, 0, 0);
            acc10 = __builtin_amdgcn_mfma_f32_32x32x16_bf16(a1, b0, acc10, 0, 0, 0);
            acc11 = __builtin_amdgcn_mfma_f32_32x32x16_bf16(a1, b1, acc11, 0, 0, 0);
        }
    }

    // ---- epilogue: C/D col(pix)=lane&31, row(co)=(reg&3)+8*(reg>>2)+4*hi
    #pragma unroll
    for (int i = 0; i < 2; ++i) {
        const f32x16& aj0 = i ? acc10 : acc00;
        const f32x16& aj1 = i ? acc11 : acc01;
        float bs[16];
        #pragma unroll
        for (int reg = 0; reg < 16; ++reg) {
            int co = coh * 64 + i * 32 + (reg & 3) + 8 * (reg >> 2) + 4 * hi;
            bs[reg] = bq[s * COUTc + co];
        }
        if (g0 < GPIX) {
            int b2 = g0 / NPIX, r2 = g0 - b2 * NPIX;
            float* ob = out + (size_t)(b2 * Sn + s) * (COUTc * NPIX) + r2;
            #pragma unroll
            for (int reg = 0; reg < 16; ++reg) {
                int co = coh * 64 + i * 32 + (reg & 3) + 8 * (reg >> 2) + 4 * hi;
                ob[co * NPIX] = aj0[reg] + bs[reg];
            }
        }
        if (g1 < GPIX) {
            int b2 = g1 / NPIX, r2 = g1 - b2 * NPIX;
            float* ob = out + (size_t)(b2 * Sn + s) * (COUTc * NPIX) + r2;
            #pragma unroll
            for (int reg = 0; reg < 16; ++reg) {
                int co = coh * 64 + i * 32 + (reg & 3) + 8 * (reg >> 2) + 4 * hi;
                ob[co * NPIX] = aj1[reg] + bs[reg];
            }
        }
    }

    // ---- KL finalize (block 0): sum the 33 partial slots
    if (bid == 0 && lane == 0) {
        float ls = 0.f, sq = 0.f;
        for (int i2 = 0; i2 < 33; ++i2) {
            ls += slots[2 * i2];
            sq += slots[2 * i2 + 1];
        }
        *klout = -ls + 0.91893853320467274f * (float)Pc + 0.5f * sq;
    }
}

// ---------------------------------------------------------------------------
extern "C" void kernel_launch(void* const* d_in, const int* in_sizes, int n_in,
                              void* d_out, int out_size, void* d_ws, size_t ws_size,
                              hipStream_t stream) {
    const float* x     = (const float*)d_in[0];
    const float* e     = (const float*)d_in[1];
    const float* mu_w  = (const float*)d_in[2];
    const float* rho_w = (const float*)d_in[3];
    const float* mu_b  = (const float*)d_in[4];
    const float* rho_b = (const float*)d_in[5];
    float* out = (float*)d_out;

    // workspace layout
    bf16*  wq    = (bf16*)d_ws;                         // 1,179,648 B
    float* bq    = (float*)((char*)d_ws + 1179648);     // 4,096 B
    float* slots = (float*)((char*)d_ws + 1183744);     // 264 B (pad to 4K)
    bf16*  xt    = (bf16*)((char*)d_ws + 1187840);      // 8,388,608 B

    prep_all<<<dim3(545), dim3(256), 0, stream>>>(
        x, e, mu_w, rho_w, mu_b, rho_b, xt, wq, bq, slots);

    conv_mfma<<<dim3(1808), dim3(64), 0, stream>>>(
        xt, wq, bq, slots, out, out + (out_size - 1));
}

// Round 8
// 36.601 us; speedup vs baseline: 1.1196x; 1.1196x over previous
//
#include <hip/hip_runtime.h>
#include <hip/hip_bf16.h>
#include <math.h>

// Problem constants
#define Bn    8
#define Sn    8
#define COUTc 128
#define PWc   73728
#define Pc    73856
#define WOc   30
#define NPIX  900      // 30*30 per (b,s)
#define GPIX  7200     // B*NPIX per s
#define NSTEP 9        // one r=(ky,kx) per K-step, 64 ci each
#define TILE  128      // pixels per block
#define NT2   57       // ceil(7200/128)

typedef __bf16 bf16;
typedef bf16  bf16x8 __attribute__((ext_vector_type(8)));
typedef float f32x16 __attribute__((ext_vector_type(16)));

__device__ __forceinline__ float softplus_f(float x) {
    return fmaxf(x, 0.f) + log1pf(expf(-fabsf(x)));
}

__device__ __forceinline__ unsigned int pack2(float a, float b) {
    unsigned short ua = __builtin_bit_cast(unsigned short, (bf16)a);
    unsigned short ub = __builtin_bit_cast(unsigned short, (bf16)b);
    return ((unsigned int)ub << 16) | (unsigned int)ua;
}

// global->LDS direct copy, 16B per lane. LDS dest = wave-uniform base
// (+ implicit lane*16); global src is per-lane.
__device__ __forceinline__ void gl16(const void* g, void* l) {
    typedef __attribute__((address_space(1))) void gvoid;
    typedef __attribute__((address_space(3))) void lvoid;
    __builtin_amdgcn_global_load_lds((gvoid*)g, (lvoid*)l, 16, 0, 0);
}

// ---------------------------------------------------------------------------
// Kernel 1 (fused):
//  blocks 0..511  : xcast  x fp32 NCHW -> xt bf16 octet-major
//                   xt chunk16[(img*8 + oct)*1024 + yx] = 8 ci of octet `oct`
//  blocks 512..543: W sampling, thread = (co,ci), 9 contiguous taps
//                   wq chunk16[(s*9+r)*1024 + oct*128 + co], oct = ci>>3
//  block  544     : bias sampling
//  Prep blocks write KL partials to slots[33*2] unconditionally.
// ---------------------------------------------------------------------------
__global__ __launch_bounds__(256) void prep_all(
        const float* __restrict__ xg, const float* __restrict__ e,
        const float* __restrict__ mu_w, const float* __restrict__ rho_w,
        const float* __restrict__ mu_b, const float* __restrict__ rho_b,
        bf16* __restrict__ xt, bf16* __restrict__ wq,
        float* __restrict__ bq, float* __restrict__ slots) {
    const int bid = blockIdx.x;
    const int t   = threadIdx.x;

    if (bid < 512) {  // ---- xcast -> octet-major
        const int img  = bid >> 3;
        const int part = bid & 7;
        const int p    = part * 128 + (t & 127);   // yx 0..1023
        const int half = t >> 7;                   // which 32-ci block
        const float* src = xg + ((size_t)img << 16) + (size_t)(half * 32) * 1024 + p;
        #pragma unroll
        for (int o = 0; o < 4; ++o) {
            uint4 pk;
            pk.x = pack2(src[(o * 8 + 0) * 1024], src[(o * 8 + 1) * 1024]);
            pk.y = pack2(src[(o * 8 + 2) * 1024], src[(o * 8 + 3) * 1024]);
            pk.z = pack2(src[(o * 8 + 4) * 1024], src[(o * 8 + 5) * 1024]);
            pk.w = pack2(src[(o * 8 + 6) * 1024], src[(o * 8 + 7) * 1024]);
            size_t idx16 = ((size_t)(img * 8 + half * 4 + o) << 10) + p;
            *reinterpret_cast<uint4*>(xt + (idx16 << 3)) = pk;
        }
        return;
    }

    float ls = 0.f, sq = 0.f;
    if (bid < 544) {  // ---- W prep: thread = one (co,ci) pair, 9 taps
        const int gidx = (bid - 512) * 256 + t;   // 0..8191
        const int co   = gidx >> 6;
        const int ci   = gidx & 63;
        const int p0   = co * 576 + ci * 9;
        float mu[9], sg[9];
        #pragma unroll
        for (int r = 0; r < 9; ++r) {
            mu[r] = mu_w[p0 + r];
            sg[r] = softplus_f(rho_w[p0 + r]);
            ls   += logf(sg[r]);
        }
        // dst bf16 index: ((s*9+r)*1024 + (ci>>3)*128 + co)*8 + (ci&7)
        const int dstp = ((((ci >> 3) << 7) + co) << 3) + (ci & 7);
        #pragma unroll
        for (int s = 0; s < Sn; ++s) {
            const float* es = e + s * Pc + p0;
            #pragma unroll
            for (int r = 0; r < 9; ++r) {
                float wv = fmaf(sg[r], es[r], mu[r]);
                wq[(((s * NSTEP + r) << 10) << 3) + dstp] = (bf16)wv;
                sq += wv * wv;
            }
        }
    } else {          // ---- bias prep (bid == 544)
        if (t < COUTc) {
            float sig = softplus_f(rho_b[t]);
            ls = logf(sig);
            float mu = mu_b[t];
            #pragma unroll
            for (int s = 0; s < Sn; ++s) {
                float bv = fmaf(sig, e[s * Pc + PWc + t], mu);
                bq[s * COUTc + t] = bv;
                sq += bv * bv;
            }
        }
    }

    #pragma unroll
    for (int off = 32; off > 0; off >>= 1) {
        ls += __shfl_down(ls, off);
        sq += __shfl_down(sq, off);
    }
    __shared__ float sls[4], ssq[4];
    const int lane = t & 63, wd = t >> 6;
    if (lane == 0) { sls[wd] = ls; ssq[wd] = sq; }
    __syncthreads();
    if (t == 0) {
        slots[2 * (bid - 512)]     = sls[0] + sls[1] + sls[2] + sls[3];
        slots[2 * (bid - 512) + 1] = ssq[0] + ssq[1] + ssq[2] + ssq[3];
    }
}

// ---------------------------------------------------------------------------
// Kernel 2: hybrid implicit-GEMM conv.
//  A (W) fragments: straight from global (octet-major wq, lane-contiguous
//  512 B, L1-resident 16 KB slice per step) -> VMEM pipe.
//  B (X) tile: gl16-staged into XOR-swizzled LDS (16 KB/buf, dbuf 32 KB).
//  Block = 256 thr (4 waves 2x2 of 64co x 64pix), tile 128co x 128pix.
//  Counted-vmcnt 2-barrier pipeline: W loads issued BEFORE the vmcnt(12)
//  wait (8 W + 4 gl16 younger than the awaited stage group).
//  s = bid&7 -> XCD-affine; KL finalize folded into block 0.
// ---------------------------------------------------------------------------
__global__ __launch_bounds__(256) void conv_mfma(
        const bf16* __restrict__ xt, const bf16* __restrict__ wq,
        const float* __restrict__ bq, const float* __restrict__ slots,
        float* __restrict__ out, float* __restrict__ klout) {
    const int bid  = blockIdx.x;
    const int s    = bid & 7;
    const int tile = bid >> 3;
    const int t    = threadIdx.x;
    const int lane = t & 63;
    const int w    = t >> 6;
    const int wr   = w >> 1;     // co half (0/1)
    const int wc   = w & 1;      // pix half (0/1)
    const int hi   = lane >> 5;  // k-octet parity
    const int lo   = lane & 31;

    __shared__ bf16 Xbuf[2][8192];    // 2 x 16 KB [pix 0..127][ci-oct swz]

    // W global A-frag base: chunk16 = (s*9+r)*1024 + (kc*2+hi)*128 + wr*64+i*32+lo
    const bf16* wbase = wq + ((((size_t)(s * NSTEP) << 10)
                               + hi * 128 + wr * 64 + lo) << 3);

    // X staging sources: wave w stages pix rows [w*32, w*32+32), 4 gl16
    const char* xs[4];
    #pragma unroll
    for (int q = 0; q < 4; ++q) {
        int pix = w * 32 + q * 8 + (lane >> 3);
        int g   = tile * TILE + pix;
        if (g >= GPIX) g = GPIX - 1;      // clamp; garbage cols discarded
        int b2 = g / NPIX, rr = g - b2 * NPIX, oy = rr / WOc, ox = rr - oy * WOc;
        int m  = (lane & 7) ^ (pix & 7);  // source ci-octet for this slot
        xs[q] = (const char*)xt
            + ((((size_t)((b2 * Sn + s) * 8 + m) << 10) + oy * 32 + ox) << 4);
    }

    f32x16 acc[2][2];
    #pragma unroll
    for (int i = 0; i < 2; ++i)
        #pragma unroll
        for (int j = 0; j < 2; ++j)
            #pragma unroll
            for (int k = 0; k < 16; ++k)
                acc[i][j][k] = 0.f;

    #define STAGE(stepc, b)                                                  \
    {                                                                        \
        const int roff_ = ((((stepc) / 3) * 32 + ((stepc) % 3)) << 4);       \
        char* xl_ = (char*)(&Xbuf[(b)][0]) + (w << 12);                      \
        gl16(xs[0] + roff_, xl_);                                            \
        gl16(xs[1] + roff_, xl_ + 1024);                                     \
        gl16(xs[2] + roff_, xl_ + 2048);                                     \
        gl16(xs[3] + roff_, xl_ + 3072);                                     \
    }

    #define ITER(tt, b, NW)                                                  \
    {                                                                        \
        bf16x8 awv[4][2];                                                    \
        _Pragma("unroll")                                                    \
        for (int kc = 0; kc < 4; ++kc)                                       \
            _Pragma("unroll")                                                \
            for (int i = 0; i < 2; ++i)                                      \
                awv[kc][i] = *reinterpret_cast<const bf16x8*>(               \
                    wbase + ((((tt) << 10) + kc * 256 + i * 32) << 3));      \
        asm volatile("s_waitcnt vmcnt(" #NW ")" ::: "memory");               \
        __builtin_amdgcn_s_barrier();                                        \
        __builtin_amdgcn_sched_barrier(0);                                   \
        const bf16* Xl_ = &Xbuf[(b)][0];                                     \
        _Pragma("unroll")                                                    \
        for (int kc = 0; kc < 4; ++kc) {                                     \
            const int oct_ = ((kc << 1) + hi) ^ (lane & 7);                  \
            bf16x8 b0 = *reinterpret_cast<const bf16x8*>(                    \
                Xl_ + ((wc * 64 + lo) << 6) + (oct_ << 3));                  \
            bf16x8 b1 = *reinterpret_cast<const bf16x8*>(                    \
                Xl_ + ((wc * 64 + 32 + lo) << 6) + (oct_ << 3));             \
            acc[0][0] = __builtin_amdgcn_mfma_f32_32x32x16_bf16(awv[kc][0], b0, acc[0][0], 0, 0, 0); \
            acc[0][1] = __builtin_amdgcn_mfma_f32_32x32x16_bf16(awv[kc][0], b1, acc[0][1], 0, 0, 0); \
            acc[1][0] = __builtin_amdgcn_mfma_f32_32x32x16_bf16(awv[kc][1], b0, acc[1][0], 0, 0, 0); \
            acc[1][1] = __builtin_amdgcn_mfma_f32_32x32x16_bf16(awv[kc][1], b1, acc[1][1], 0, 0, 0); \
        }                                                                    \
        __builtin_amdgcn_sched_barrier(0);                                   \
        __builtin_amdgcn_s_barrier();                                        \
        if ((tt) + 2 <= 8) STAGE((tt) + 2, b);                               \
    }

    // prologue: two X stages in flight
    STAGE(0, 0);
    STAGE(1, 1);

    ITER(0, 0, 12)
    ITER(1, 1, 12)
    ITER(2, 0, 12)
    ITER(3, 1, 12)
    ITER(4, 0, 12)
    ITER(5, 1, 12)
    ITER(6, 0, 12)
    ITER(7, 1, 12)
    ITER(8, 0, 8)

    #undef ITER
    #undef STAGE

    // ---- epilogue: 32x32 C/D: col(pix)=lane&31, row(co)=(reg&3)+8*(reg>>2)+4*hi
    #pragma unroll
    for (int i = 0; i < 2; ++i) {
        float bs[16];
        #pragma unroll
        for (int reg = 0; reg < 16; ++reg) {
            int co = wr * 64 + i * 32 + (reg & 3) + 8 * (reg >> 2) + 4 * hi;
            bs[reg] = bq[s * COUTc + co];
        }
        #pragma unroll
        for (int j = 0; j < 2; ++j) {
            int gg = tile * TILE + wc * 64 + j * 32 + lo;
            if (gg >= GPIX) continue;
            int b2 = gg / NPIX;
            int r2 = gg - b2 * NPIX;
            float* ob = out + (size_t)(b2 * Sn + s) * (COUTc * NPIX) + r2;
            #pragma unroll
            for (int reg = 0; reg < 16; ++reg) {
                int co = wr * 64 + i * 32 + (reg & 3) + 8 * (reg >> 2) + 4 * hi;
                ob[co * NPIX] = acc[i][j][reg] + bs[reg];
            }
        }
    }

    // ---- KL finalize (block 0): sum the 33 partial slots
    if (bid == 0 && t == 0) {
        float ls = 0.f, sq = 0.f;
        for (int i2 = 0; i2 < 33; ++i2) {
            ls += slots[2 * i2];
            sq += slots[2 * i2 + 1];
        }
        *klout = -ls + 0.91893853320467274f * (float)Pc + 0.5f * sq;
    }
}

// ---------------------------------------------------------------------------
extern "C" void kernel_launch(void* const* d_in, const int* in_sizes, int n_in,
                              void* d_out, int out_size, void* d_ws, size_t ws_size,
                              hipStream_t stream) {
    const float* x     = (const float*)d_in[0];
    const float* e     = (const float*)d_in[1];
    const float* mu_w  = (const float*)d_in[2];
    const float* rho_w = (const float*)d_in[3];
    const float* mu_b  = (const float*)d_in[4];
    const float* rho_b = (const float*)d_in[5];
    float* out = (float*)d_out;

    // workspace layout
    bf16*  wq    = (bf16*)d_ws;                         // 1,179,648 B
    float* bq    = (float*)((char*)d_ws + 1179648);     // 4,096 B
    float* slots = (float*)((char*)d_ws + 1183744);     // 264 B (pad to 4K)
    bf16*  xt    = (bf16*)((char*)d_ws + 1187840);      // 8,388,608 B

    prep_all<<<dim3(545), dim3(256), 0, stream>>>(
        x, e, mu_w, rho_w, mu_b, rho_b, xt, wq, bq, slots);

    conv_mfma<<<dim3(NT2 * Sn), dim3(256), 0, stream>>>(
        xt, wq, bq, slots, out, out + (out_size - 1));
}

// Round 9
// 33.495 us; speedup vs baseline: 1.2234x; 1.0928x over previous
//
#include <hip/hip_runtime.h>
#include <hip/hip_bf16.h>
#include <math.h>

// Problem constants
#define Bn    8
#define Sn    8
#define COUTc 128
#define PWc   73728
#define Pc    73856
#define WOc   30
#define NPIX  900      // 30*30 per (b,s)
#define GPIX  7200     // B*NPIX per s
#define NSTEP 9        // one r=(ky,kx) per K-step, 64 ci each
#define TILE  128      // pixels per block
#define NT2   57       // ceil(7200/128)

typedef __bf16 bf16;
typedef bf16  bf16x8 __attribute__((ext_vector_type(8)));
typedef float f32x4v __attribute__((ext_vector_type(4)));
typedef float f32x16 __attribute__((ext_vector_type(16)));

__device__ __forceinline__ float softplus_f(float x) {
    return fmaxf(x, 0.f) + log1pf(expf(-fabsf(x)));
}

__device__ __forceinline__ unsigned int pack2(float a, float b) {
    unsigned short ua = __builtin_bit_cast(unsigned short, (bf16)a);
    unsigned short ub = __builtin_bit_cast(unsigned short, (bf16)b);
    return ((unsigned int)ub << 16) | (unsigned int)ua;
}

// global->LDS direct copy, 16B per lane. LDS dest = wave-uniform base
// (+ implicit lane*16); global src is per-lane.
__device__ __forceinline__ void gl16(const void* g, void* l) {
    typedef __attribute__((address_space(1))) void gvoid;
    typedef __attribute__((address_space(3))) void lvoid;
    __builtin_amdgcn_global_load_lds((gvoid*)g, (lvoid*)l, 16, 0, 0);
}

// ---------------------------------------------------------------------------
// Kernel 1 (fused):
//  blocks 0..511  : xcast  x fp32 NCHW -> xt bf16 channels-last [img][yx][ci]
//                   (12 VMEM instr/thread: 8 float4 loads + 4 uint4 stores)
//  blocks 512..543: W sampling, thread = (co,ci), 9 contiguous taps, into the
//                   swizzled per-(s,r) LDS images (R5 layout)
//  block  544     : bias sampling
//  Prep blocks write KL partials to slots[33*2] unconditionally.
//  wimg page (s,r): element (co<<6) + (((ci>>3)^(co&7))<<3) + (ci&7).
// ---------------------------------------------------------------------------
__global__ __launch_bounds__(256) void prep_all(
        const float* __restrict__ xg, const float* __restrict__ e,
        const float* __restrict__ mu_w, const float* __restrict__ rho_w,
        const float* __restrict__ mu_b, const float* __restrict__ rho_b,
        bf16* __restrict__ xt, bf16* __restrict__ wimg,
        float* __restrict__ bq, float* __restrict__ slots) {
    const int bid = blockIdx.x;
    const int t   = threadIdx.x;

    if (bid < 512) {  // ---- xcast: thread = (oct, 4 consecutive pixels)
        const int img = bid >> 3;
        const int oct = t & 7;                       // ci octet
        const int p0  = ((bid & 7) * 32 + (t >> 3)) * 4;  // yx 0..1020
        const float* src = xg + ((size_t)img << 16) + (size_t)(oct * 8) * 1024 + p0;
        f32x4v v[8];
        #pragma unroll
        for (int j = 0; j < 8; ++j)
            v[j] = *reinterpret_cast<const f32x4v*>(src + (size_t)j * 1024);
        // dst: [img][p][ci] channels-last, 128 B per pixel, 16 B per octet
        char* dstB = (char*)xt + (((size_t)(img << 10) + p0) << 7) + (oct << 4);
        #pragma unroll
        for (int i = 0; i < 4; ++i) {
            uint4 pk;
            pk.x = pack2(v[0][i], v[1][i]);
            pk.y = pack2(v[2][i], v[3][i]);
            pk.z = pack2(v[4][i], v[5][i]);
            pk.w = pack2(v[6][i], v[7][i]);
            *reinterpret_cast<uint4*>(dstB + (size_t)i * 128) = pk;
        }
        return;
    }

    float ls = 0.f, sq = 0.f;
    if (bid < 544) {  // ---- W prep: thread = one (co,ci) pair, 9 taps
        const int gidx = (bid - 512) * 256 + t;   // 0..8191
        const int co   = gidx >> 6;
        const int ci   = gidx & 63;
        const int p0   = co * 576 + ci * 9;
        float mu[9], sg[9];
        #pragma unroll
        for (int r = 0; r < 9; ++r) {
            mu[r] = mu_w[p0 + r];
            sg[r] = softplus_f(rho_w[p0 + r]);
            ls   += logf(sg[r]);
        }
        const int dstp = (co << 6) + (((ci >> 3) ^ (co & 7)) << 3) + (ci & 7);
        #pragma unroll
        for (int s = 0; s < Sn; ++s) {
            const float* es = e + s * Pc + p0;
            #pragma unroll
            for (int r = 0; r < 9; ++r) {
                float wv = fmaf(sg[r], es[r], mu[r]);
                wimg[((s * NSTEP + r) << 13) + dstp] = (bf16)wv;
                sq += wv * wv;
            }
        }
    } else {          // ---- bias prep (bid == 544)
        if (t < COUTc) {
            float sig = softplus_f(rho_b[t]);
            ls = logf(sig);
            float mu = mu_b[t];
            #pragma unroll
            for (int s = 0; s < Sn; ++s) {
                float bv = fmaf(sig, e[s * Pc + PWc + t], mu);
                bq[s * COUTc + t] = bv;
                sq += bv * bv;
            }
        }
    }

    #pragma unroll
    for (int off = 32; off > 0; off >>= 1) {
        ls += __shfl_down(ls, off);
        sq += __shfl_down(sq, off);
    }
    __shared__ float sls[4], ssq[4];
    const int lane = t & 63, wd = t >> 6;
    if (lane == 0) { sls[wd] = ls; ssq[wd] = sq; }
    __syncthreads();
    if (t == 0) {
        slots[2 * (bid - 512)]     = sls[0] + sls[1] + sls[2] + sls[3];
        slots[2 * (bid - 512) + 1] = ssq[0] + ssq[1] + ssq[2] + ssq[3];
    }
}

// ---------------------------------------------------------------------------
// Kernel 2: implicit-GEMM conv — R5's proven structure with SINGLE barrier
// per K-step (T3 minimum-2-phase): STAGE(t+1,buf^1) -> COMPUTE(buf) ->
// vmcnt(0) -> s_barrier. WAR on buf^1 covered by previous iteration's
// barrier. Block = 256 thr (4 waves 2x2 of 64co x 64pix), tile 128x128,
// mfma_f32_32x32x16_bf16, all staging via global_load_lds with the XOR
// swizzle pre-baked in the global sources. LDS 64 KB dbuf -> 2 blocks/CU.
// s = bid&7 -> XCD-affine; KL finalize folded into block 0.
// ---------------------------------------------------------------------------
__global__ __launch_bounds__(256) void conv_mfma(
        const bf16* __restrict__ xt, const bf16* __restrict__ wimg,
        const float* __restrict__ bq, const float* __restrict__ slots,
        float* __restrict__ out, float* __restrict__ klout) {
    const int bid  = blockIdx.x;
    const int s    = bid & 7;
    const int tile = bid >> 3;
    const int t    = threadIdx.x;
    const int lane = t & 63;
    const int w    = t >> 6;
    const int wr   = w >> 1;     // co half (0/1)
    const int wc   = w & 1;      // pix half (0/1)

    __shared__ bf16 Wbuf[2][8192];   // 2 x 16 KB  [co 0..127][ci-oct swz]
    __shared__ bf16 Xbuf[2][8192];   // 2 x 16 KB  [pix 0..127][ci-oct swz]

    // W staging source: wimg page is the exact LDS byte image
    const char* wsrcL = (const char*)wimg + ((size_t)(s * NSTEP) << 14)
                      + (w << 12) + (lane << 4);

    // X staging sources: wave w stages pix rows [w*32, w*32+32), 4 gl16
    const char *x0, *x1, *x2, *x3;
    #pragma unroll
    for (int q = 0; q < 4; ++q) {
        int pix = w * 32 + q * 8 + (lane >> 3);
        int g   = tile * TILE + pix;
        if (g >= GPIX) g = GPIX - 1;      // clamp; garbage cols discarded
        int b2 = g / NPIX, rr = g - b2 * NPIX, oy = rr / WOc, ox = rr - oy * WOc;
        int m  = (lane & 7) ^ (pix & 7);  // source ci-octet for this slot
        const char* ptr = (const char*)xt
            + ((((size_t)(b2 * Sn + s) << 10) + oy * 32 + ox) << 7) + (m << 4);
        if (q == 0) x0 = ptr; else if (q == 1) x1 = ptr;
        else if (q == 2) x2 = ptr; else x3 = ptr;
    }

    f32x16 acc[2][2];
    #pragma unroll
    for (int i = 0; i < 2; ++i)
        #pragma unroll
        for (int j = 0; j < 2; ++j)
            #pragma unroll
            for (int k = 0; k < 16; ++k)
                acc[i][j][k] = 0.f;

    #define STAGE(stepc, b)                                                  \
    {                                                                        \
        const char* ws_ = wsrcL + ((stepc) << 14);                           \
        char* wl_ = (char*)(&Wbuf[(b)][0]) + (w << 12);                      \
        gl16(ws_,        wl_);                                               \
        gl16(ws_ + 1024, wl_ + 1024);                                        \
        gl16(ws_ + 2048, wl_ + 2048);                                        \
        gl16(ws_ + 3072, wl_ + 3072);                                        \
        const int roff_ = (((stepc) / 3) * 32 + ((stepc) % 3)) * 128;        \
        char* xl_ = (char*)(&Xbuf[(b)][0]) + (w << 12);                      \
        gl16(x0 + roff_, xl_);                                               \
        gl16(x1 + roff_, xl_ + 1024);                                        \
        gl16(x2 + roff_, xl_ + 2048);                                        \
        gl16(x3 + roff_, xl_ + 3072);                                        \
    }

    #define COMPUTE(b)                                                       \
    {                                                                        \
        const bf16* Wl_ = &Wbuf[(b)][0];                                     \
        const bf16* Xl_ = &Xbuf[(b)][0];                                     \
        _Pragma("unroll")                                                    \
        for (int kc = 0; kc < 4; ++kc) {                                     \
            const int oct_ = ((kc << 1) + (lane >> 5)) ^ (lane & 7);         \
            bf16x8 af0 = *reinterpret_cast<const bf16x8*>(                   \
                Wl_ + ((wr * 64 + (lane & 31)) << 6) + (oct_ << 3));         \
            bf16x8 af1 = *reinterpret_cast<const bf16x8*>(                   \
                Wl_ + ((wr * 64 + 32 + (lane & 31)) << 6) + (oct_ << 3));    \
            bf16x8 bf0 = *reinterpret_cast<const bf16x8*>(                   \
                Xl_ + ((wc * 64 + (lane & 31)) << 6) + (oct_ << 3));         \
            bf16x8 bf1 = *reinterpret_cast<const bf16x8*>(                   \
                Xl_ + ((wc * 64 + 32 + (lane & 31)) << 6) + (oct_ << 3));    \
            acc[0][0] = __builtin_amdgcn_mfma_f32_32x32x16_bf16(af0, bf0, acc[0][0], 0, 0, 0); \
            acc[0][1] = __builtin_amdgcn_mfma_f32_32x32x16_bf16(af0, bf1, acc[0][1], 0, 0, 0); \
            acc[1][0] = __builtin_amdgcn_mfma_f32_32x32x16_bf16(af1, bf0, acc[1][0], 0, 0, 0); \
            acc[1][1] = __builtin_amdgcn_mfma_f32_32x32x16_bf16(af1, bf1, acc[1][1], 0, 0, 0); \
        }                                                                    \
    }

    // prologue: stage step 0, drain, sync
    STAGE(0, 0);
    asm volatile("s_waitcnt vmcnt(0)" ::: "memory");
    __builtin_amdgcn_s_barrier();
    __builtin_amdgcn_sched_barrier(0);

    // single barrier per step: stage next (other buf) -> compute -> wait+bar
    #define ITER(tt)                                                         \
        STAGE((tt) + 1, ((tt) + 1) & 1);                                     \
        COMPUTE((tt) & 1);                                                   \
        asm volatile("s_waitcnt vmcnt(0)" ::: "memory");                     \
        __builtin_amdgcn_s_barrier();                                        \
        __builtin_amdgcn_sched_barrier(0);

    ITER(0)
    ITER(1)
    ITER(2)
    ITER(3)
    ITER(4)
    ITER(5)
    ITER(6)
    ITER(7)
    COMPUTE(0);   // step 8, no further stage

    #undef ITER
    #undef COMPUTE
    #undef STAGE

    // ---- epilogue: 32x32 C/D: col(pix)=lane&31, row(co)=(reg&3)+8*(reg>>2)+4*(lane>>5)
    const int colp = lane & 31;
    const int hi   = lane >> 5;
    #pragma unroll
    for (int ti = 0; ti < 2; ++ti) {
        float bs[16];
        #pragma unroll
        for (int reg = 0; reg < 16; ++reg) {
            int co = wr * 64 + ti * 32 + (reg & 3) + 8 * (reg >> 2) + 4 * hi;
            bs[reg] = bq[s * COUTc + co];
        }
        #pragma unroll
        for (int tj = 0; tj < 2; ++tj) {
            int gg = tile * TILE + wc * 64 + tj * 32 + colp;
            if (gg >= GPIX) continue;
            int b2 = gg / NPIX;
            int r2 = gg - b2 * NPIX;
            float* ob = out + (size_t)(b2 * Sn + s) * (COUTc * NPIX) + r2;
            #pragma unroll
            for (int reg = 0; reg < 16; ++reg) {
                int co = wr * 64 + ti * 32 + (reg & 3) + 8 * (reg >> 2) + 4 * hi;
                ob[co * NPIX] = acc[ti][tj][reg] + bs[reg];
            }
        }
    }

    // ---- KL finalize (block 0): sum the 33 partial slots
    if (bid == 0 && t == 0) {
        float ls = 0.f, sq = 0.f;
        for (int i2 = 0; i2 < 33; ++i2) {
            ls += slots[2 * i2];
            sq += slots[2 * i2 + 1];
        }
        *klout = -ls + 0.91893853320467274f * (float)Pc + 0.5f * sq;
    }
}

// ---------------------------------------------------------------------------
extern "C" void kernel_launch(void* const* d_in, const int* in_sizes, int n_in,
                              void* d_out, int out_size, void* d_ws, size_t ws_size,
                              hipStream_t stream) {
    const float* x     = (const float*)d_in[0];
    const float* e     = (const float*)d_in[1];
    const float* mu_w  = (const float*)d_in[2];
    const float* rho_w = (const float*)d_in[3];
    const float* mu_b  = (const float*)d_in[4];
    const float* rho_b = (const float*)d_in[5];
    float* out = (float*)d_out;

    // workspace layout
    bf16*  wimg  = (bf16*)d_ws;                         // 1,179,648 B
    float* bq    = (float*)((char*)d_ws + 1179648);     // 4,096 B
    float* slots = (float*)((char*)d_ws + 1183744);     // 264 B (pad to 4K)
    bf16*  xt    = (bf16*)((char*)d_ws + 1187840);      // 8,388,608 B

    prep_all<<<dim3(545), dim3(256), 0, stream>>>(
        x, e, mu_w, rho_w, mu_b, rho_b, xt, wimg, bq, slots);

    conv_mfma<<<dim3(NT2 * Sn), dim3(256), 0, stream>>>(
        xt, wimg, bq, slots, out, out + (out_size - 1));
}